// Round 1
// baseline (789.868 us; speedup 1.0000x reference)
//
#include <hip/hip_runtime.h>
#include <stdint.h>

// AttentionBlock: B=32, C=512, H=W=32 (N=1024), fp32 in/out.
// Pipeline (all intermediates bf16 in d_ws, ~194 MB used):
//   cvt weights -> bf16 ; transpose x -> Xt[B,N,C] bf16
//   Q = Xt*Wq^T + bq  [B*N, C]
//   K = Xt*Wk^T + bk  [B*N, C]
//   V = Wv*Xt_b^T+bv  [B][C][N]   (so PV step stays in B-transposed GEMM form)
//   S = Q_b*K_b^T * 1/sqrt(C)  [B][N][N] ; row softmax in-place
//   Hh = P_b * V_b(form)  [B][N][C]
//   out = Wo*Hh_b^T + bo + x   [B][C][N] fp32

#define CD 512
#define NSP 1024
#define NB 32

using bf16x8 = __attribute__((ext_vector_type(8))) short;
using f32x4  = __attribute__((ext_vector_type(4))) float;

__device__ __forceinline__ float bf2f(unsigned short u) {
    union { unsigned int i; float f; } v; v.i = ((unsigned int)u) << 16; return v.f;
}
__device__ __forceinline__ unsigned short f2bf(float f) {
    union { float f; unsigned int i; } v; v.f = f;
    unsigned int r = v.i + 0x7FFFu + ((v.i >> 16) & 1u);
    return (unsigned short)(r >> 16);
}

__global__ __launch_bounds__(256) void cvt_w(const float* __restrict__ in,
                                             unsigned short* __restrict__ out, int n) {
    int i = blockIdx.x * 256 + threadIdx.x;
    if (i < n) out[i] = f2bf(in[i]);
}

// x [B][C][N] f32 -> xt [B][N][C] bf16
__global__ __launch_bounds__(256) void transpose_x(const float* __restrict__ x,
                                                   unsigned short* __restrict__ xt) {
    __shared__ float t[32][33];
    int b = blockIdx.z;
    int n0 = blockIdx.x * 32, c0 = blockIdx.y * 32;
    const float* xb = x + (size_t)b * CD * NSP;
    unsigned short* xtb = xt + (size_t)b * NSP * CD;
    int tx = threadIdx.x, ty = threadIdx.y;
    #pragma unroll
    for (int i = 0; i < 4; ++i)
        t[ty + i * 8][tx] = xb[(size_t)(c0 + ty + i * 8) * NSP + n0 + tx];
    __syncthreads();
    #pragma unroll
    for (int i = 0; i < 4; ++i)
        xtb[(size_t)(n0 + ty + i * 8) * CD + c0 + tx] = f2bf(t[tx][ty + i * 8]);
}

// C[m][n] = alpha * sum_k A[m][k]*B[n][k]  (+bias[n]|bias[m]) (+resid) ; bf16 in
// 128x128 tile, BK=64, 256 thr = 4 waves each 64x64 (4x4 frags of 16x16x32).
// LDS XOR swizzle: 16B-chunk kc stored at (kc ^ (row&7)) within the 128B row.
template<int BIAS_MODE, bool RESID, bool OUT_F32>
__global__ __launch_bounds__(256)
void gemm_bt(const unsigned short* __restrict__ A,
             const unsigned short* __restrict__ B,
             void* __restrict__ Cv,
             const float* __restrict__ bias,
             const float* __restrict__ resid,
             int K, int lda, int ldb, int ldc,
             long sA, long sB, long sC, long sR, float alpha)
{
    __shared__ __align__(16) unsigned short As[128 * 64];
    __shared__ __align__(16) unsigned short Bs[128 * 64];

    const int z = blockIdx.z;
    const unsigned short* Ab = A + (size_t)z * sA + (size_t)blockIdx.y * 128 * lda;
    const unsigned short* Bb = B + (size_t)z * sB + (size_t)blockIdx.x * 128 * ldb;

    const int t = threadIdx.x;
    const int lane = t & 63;
    const int wave = t >> 6;
    const int wr = wave >> 1, wc = wave & 1;
    const int lr = lane & 15, lk = lane >> 4;

    const int str = t >> 3;   // staging row base (0..31)
    const int skc = t & 7;    // staging 16B chunk (0..7)

    f32x4 zero = {0.f, 0.f, 0.f, 0.f};
    f32x4 acc[4][4];
    #pragma unroll
    for (int i = 0; i < 4; ++i)
        #pragma unroll
        for (int j = 0; j < 4; ++j) acc[i][j] = zero;

    for (int k0 = 0; k0 < K; k0 += 64) {
        int4 ra[4], rb[4];
        #pragma unroll
        for (int i = 0; i < 4; ++i) {
            ra[i] = *(const int4*)(Ab + (size_t)(i * 32 + str) * lda + k0 + skc * 8);
            rb[i] = *(const int4*)(Bb + (size_t)(i * 32 + str) * ldb + k0 + skc * 8);
        }
        __syncthreads();   // previous iter's LDS reads complete
        #pragma unroll
        for (int i = 0; i < 4; ++i) {
            int r = i * 32 + str;
            *(int4*)&As[(r << 6) + ((skc ^ (r & 7)) << 3)] = ra[i];
            *(int4*)&Bs[(r << 6) + ((skc ^ (r & 7)) << 3)] = rb[i];
        }
        __syncthreads();
        #pragma unroll
        for (int kk = 0; kk < 2; ++kk) {
            bf16x8 af[4], bfr[4];
            #pragma unroll
            for (int f = 0; f < 4; ++f) {
                int arow = wr * 64 + f * 16 + lr;
                af[f] = *(const bf16x8*)&As[(arow << 6) + ((((kk << 2) | lk) ^ (arow & 7)) << 3)];
                int brow = wc * 64 + f * 16 + lr;
                bfr[f] = *(const bf16x8*)&Bs[(brow << 6) + ((((kk << 2) | lk) ^ (brow & 7)) << 3)];
            }
            #pragma unroll
            for (int fm = 0; fm < 4; ++fm)
                #pragma unroll
                for (int fn = 0; fn < 4; ++fn)
                    acc[fm][fn] = __builtin_amdgcn_mfma_f32_16x16x32_bf16(
                        af[fm], bfr[fn], acc[fm][fn], 0, 0, 0);
        }
    }

    const int m0 = blockIdx.y * 128;
    const int n0 = blockIdx.x * 128;
    float* Cf = (float*)Cv + (size_t)z * sC;
    unsigned short* Ch = (unsigned short*)Cv + (size_t)z * sC;
    const float* rp = resid ? resid + (size_t)z * sR : nullptr;

    #pragma unroll
    for (int fm = 0; fm < 4; ++fm) {
        #pragma unroll
        for (int fn = 0; fn < 4; ++fn) {
            int col = n0 + wc * 64 + fn * 16 + lr;          // D col = lane&15
            int rowb = m0 + wr * 64 + fm * 16 + lk * 4;     // D row = 4*(lane>>4)+j
            #pragma unroll
            for (int j = 0; j < 4; ++j) {
                int row = rowb + j;
                float v = acc[fm][fn][j] * alpha;
                if (BIAS_MODE == 1) v += bias[col];
                if (BIAS_MODE == 2) v += bias[row];
                if (RESID) v += rp[(size_t)row * ldc + col];
                if (OUT_F32) Cf[(size_t)row * ldc + col] = v;
                else         Ch[(size_t)row * ldc + col] = f2bf(v);
            }
        }
    }
}

// In-place row softmax over [rows][1024] bf16; one wave per row.
__global__ __launch_bounds__(256) void softmax_rows(unsigned short* __restrict__ S) {
    size_t row = (size_t)blockIdx.x * 4 + (threadIdx.x >> 6);
    int lane = threadIdx.x & 63;
    unsigned short* r = S + row * 1024;
    union { int4 v; unsigned short u[8]; } a0, a1;
    a0.v = *(const int4*)(r + lane * 8);
    a1.v = *(const int4*)(r + 512 + lane * 8);
    float v[16];
    #pragma unroll
    for (int i = 0; i < 8; ++i) { v[i] = bf2f(a0.u[i]); v[8 + i] = bf2f(a1.u[i]); }
    float mx = -3.4e38f;
    #pragma unroll
    for (int i = 0; i < 16; ++i) mx = fmaxf(mx, v[i]);
    #pragma unroll
    for (int off = 32; off; off >>= 1) mx = fmaxf(mx, __shfl_xor(mx, off));
    float s = 0.f;
    #pragma unroll
    for (int i = 0; i < 16; ++i) { v[i] = __expf(v[i] - mx); s += v[i]; }
    #pragma unroll
    for (int off = 32; off; off >>= 1) s += __shfl_xor(s, off);
    float inv = 1.f / s;
    #pragma unroll
    for (int i = 0; i < 8; ++i) { a0.u[i] = f2bf(v[i] * inv); a1.u[i] = f2bf(v[8 + i] * inv); }
    *(int4*)(r + lane * 8) = a0.v;
    *(int4*)(r + 512 + lane * 8) = a1.v;
}

extern "C" void kernel_launch(void* const* d_in, const int* in_sizes, int n_in,
                              void* d_out, int out_size, void* d_ws, size_t ws_size,
                              hipStream_t stream)
{
    const float* x  = (const float*)d_in[0];
    const float* Wq = (const float*)d_in[1];
    const float* bq = (const float*)d_in[2];
    const float* Wk = (const float*)d_in[3];
    const float* bk = (const float*)d_in[4];
    const float* Wv = (const float*)d_in[5];
    const float* bv = (const float*)d_in[6];
    const float* Wo = (const float*)d_in[7];
    const float* bo = (const float*)d_in[8];
    float* out = (float*)d_out;

    // workspace layout (ushort units); total ~194 MB
    unsigned short* w   = (unsigned short*)d_ws;
    unsigned short* Wqb = w;
    unsigned short* Wkb = Wqb + 262144;
    unsigned short* Wvb = Wkb + 262144;
    unsigned short* Wob = Wvb + 262144;
    unsigned short* Xt  = Wob + 262144;      // [B][N][C]  16M elems
    unsigned short* Qb  = Xt + 16777216;     // [B][N][C]
    unsigned short* Kb  = Qb + 16777216;     // [B][N][C]
    unsigned short* Vc  = Kb + 16777216;     // [B][C][N]
    unsigned short* Sb  = Vc + 16777216;     // [B][N][N]  32M elems
    unsigned short* Hb  = Xt;                // reuse Xt (dead after V gemm)

    cvt_w<<<1024, 256, 0, stream>>>(Wq, Wqb, 262144);
    cvt_w<<<1024, 256, 0, stream>>>(Wk, Wkb, 262144);
    cvt_w<<<1024, 256, 0, stream>>>(Wv, Wvb, 262144);
    cvt_w<<<1024, 256, 0, stream>>>(Wo, Wob, 262144);
    transpose_x<<<dim3(32, 16, 32), dim3(32, 8), 0, stream>>>(x, Xt);

    // Q,K: [32768,512] = Xt * W^T + b(col)
    gemm_bt<1, false, false><<<dim3(4, 256, 1), 256, 0, stream>>>(
        Xt, Wqb, Qb, bq, nullptr, 512, 512, 512, 512, 0, 0, 0, 0, 1.0f);
    gemm_bt<1, false, false><<<dim3(4, 256, 1), 256, 0, stream>>>(
        Xt, Wkb, Kb, bk, nullptr, 512, 512, 512, 512, 0, 0, 0, 0, 1.0f);

    // V in [C][N]: A=Wv [C,C], B=Xt_b [N,C], bias per-row(c)
    gemm_bt<2, false, false><<<dim3(8, 4, 32), 256, 0, stream>>>(
        Wvb, Xt, Vc, bv, nullptr, 512, 512, 512, 1024, 0, 524288, 524288, 0, 1.0f);

    // S = Q_b * K_b^T * 1/sqrt(512)
    gemm_bt<0, false, false><<<dim3(8, 8, 32), 256, 0, stream>>>(
        Qb, Kb, Sb, nullptr, nullptr, 512, 512, 512, 1024,
        524288, 524288, 1048576, 0, 0.04419417382f);

    softmax_rows<<<8192, 256, 0, stream>>>(Sb);

    // Hh = P_b [1024,1024] * V_b (B stored [c][m]) -> [1024,512]
    gemm_bt<0, false, false><<<dim3(4, 8, 32), 256, 0, stream>>>(
        Sb, Vc, Hb, nullptr, nullptr, 1024, 1024, 1024, 512,
        1048576, 524288, 524288, 0, 1.0f);

    // out = Wo * Hh_b^T + bo(row) + x   [C][N] fp32
    gemm_bt<2, true, true><<<dim3(8, 4, 32), 256, 0, stream>>>(
        Wob, Hb, out, bo, x, 512, 512, 512, 1024,
        0, 524288, 524288, 524288, 1.0f);
}

// Round 2
// 286.985 us; speedup vs baseline: 2.7523x; 2.7523x over previous
//
#include <hip/hip_runtime.h>
#include <stdint.h>

// AttentionBlock: B=32, C=512, H=W=32 (N=1024), fp32 in/out.
//   cvt weights -> bf16 ; transpose x -> Xt[B,N,C] bf16
//   Q = (Xt*Wq^T + bq) * C^-0.5   [B*N, C]   (scale folded into projection)
//   K = Xt*Wk^T + bk              [B*N, C]
//   V = Wv*Xt_b^T + bv            [B][C][N]
//   H = flash_attn(Q,K,V)         [B][N][C]  (fused S/softmax/PV, no S matrix)
//   out = Wo*H_b^T + bo + x       [B][C][N] fp32

#define CD 512
#define NSP 1024

using bf16x8 = __attribute__((ext_vector_type(8))) short;
using f32x4  = __attribute__((ext_vector_type(4))) float;

__device__ __forceinline__ float bf2f(unsigned short u) {
    union { unsigned int i; float f; } v; v.i = ((unsigned int)u) << 16; return v.f;
}
__device__ __forceinline__ unsigned short f2bf(float f) {
    union { float f; unsigned int i; } v; v.f = f;
    unsigned int r = v.i + 0x7FFFu + ((v.i >> 16) & 1u);
    return (unsigned short)(r >> 16);
}
// async global->LDS, 16B per lane; lds base must be wave-uniform (dest = base + lane*16)
__device__ __forceinline__ void gl_lds16(const unsigned short* g, unsigned short* l) {
    __builtin_amdgcn_global_load_lds(
        (const __attribute__((address_space(1))) void*)g,
        (__attribute__((address_space(3))) void*)l, 16, 0, 0);
}

__global__ __launch_bounds__(256) void cvt_w(const float* __restrict__ in,
                                             unsigned short* __restrict__ out, int n) {
    int i = blockIdx.x * 256 + threadIdx.x;
    if (i < n) out[i] = f2bf(in[i]);
}

// x [B][C][N] f32 -> xt [B][N][C] bf16
__global__ __launch_bounds__(256) void transpose_x(const float* __restrict__ x,
                                                   unsigned short* __restrict__ xt) {
    __shared__ float t[32][33];
    int b = blockIdx.z;
    int n0 = blockIdx.x * 32, c0 = blockIdx.y * 32;
    const float* xb = x + (size_t)b * CD * NSP;
    unsigned short* xtb = xt + (size_t)b * NSP * CD;
    int tx = threadIdx.x, ty = threadIdx.y;
    #pragma unroll
    for (int i = 0; i < 4; ++i)
        t[ty + i * 8][tx] = xb[(size_t)(c0 + ty + i * 8) * NSP + n0 + tx];
    __syncthreads();
    #pragma unroll
    for (int i = 0; i < 4; ++i)
        xtb[(size_t)(n0 + ty + i * 8) * CD + c0 + tx] = f2bf(t[tx][ty + i * 8]);
}

// C[m][n] = alpha * (sum_k A[m][k]*B[n][k] + bias) (+resid) ; bf16 in
// 128x128 tile, BK=64, 4 waves (64x64 each). global_load_lds staging with
// pre-swizzled SOURCE (chunk ^= row&7), linear LDS dest, XOR on read.
template<int BIAS_MODE, bool RESID, bool OUT_F32>
__global__ __launch_bounds__(256)
void gemm_bt(const unsigned short* __restrict__ A,
             const unsigned short* __restrict__ B,
             void* __restrict__ Cv,
             const float* __restrict__ bias,
             const float* __restrict__ resid,
             int K, int lda, int ldb, int ldc,
             long sA, long sB, long sC, long sR, float alpha)
{
    __shared__ __align__(16) unsigned short As[128 * 64];
    __shared__ __align__(16) unsigned short Bs[128 * 64];

    const int z = blockIdx.z;
    const unsigned short* Ab = A + (size_t)z * sA + (size_t)blockIdx.y * 128 * lda;
    const unsigned short* Bb = B + (size_t)z * sB + (size_t)blockIdx.x * 128 * ldb;

    const int t = threadIdx.x;
    const int lane = t & 63;
    const int wave = t >> 6;
    const int wr = wave >> 1, wc = wave & 1;
    const int lr = lane & 15, lk = lane >> 4;

    f32x4 acc[4][4] = {};

    for (int k0 = 0; k0 < K; k0 += 64) {
        __syncthreads();   // previous iter's LDS reads complete
        #pragma unroll
        for (int i = 0; i < 4; ++i) {
            int rb = i * 32 + wave * 8;          // wave-uniform base row (8 rows/call)
            int row = rb + (lane >> 3);
            int ch = (lane & 7) ^ (row & 7);     // pre-swizzled source chunk
            gl_lds16(Ab + (size_t)row * lda + k0 + ch * 8, &As[rb * 64]);
            gl_lds16(Bb + (size_t)row * ldb + k0 + ch * 8, &Bs[rb * 64]);
        }
        __syncthreads();   // waits vmcnt(0): staging landed
        #pragma unroll
        for (int kk = 0; kk < 2; ++kk) {
            bf16x8 af[4], bfr[4];
            #pragma unroll
            for (int f = 0; f < 4; ++f) {
                int arow = wr * 64 + f * 16 + lr;
                af[f] = *(const bf16x8*)&As[(arow << 6) + ((((kk << 2) | lk) ^ (arow & 7)) << 3)];
                int brow = wc * 64 + f * 16 + lr;
                bfr[f] = *(const bf16x8*)&Bs[(brow << 6) + ((((kk << 2) | lk) ^ (brow & 7)) << 3)];
            }
            #pragma unroll
            for (int fm = 0; fm < 4; ++fm)
                #pragma unroll
                for (int fn = 0; fn < 4; ++fn)
                    acc[fm][fn] = __builtin_amdgcn_mfma_f32_16x16x32_bf16(
                        af[fm], bfr[fn], acc[fm][fn], 0, 0, 0);
        }
    }

    const int m0 = blockIdx.y * 128;
    const int n0 = blockIdx.x * 128;
    float* Cf = (float*)Cv + (size_t)z * sC;
    unsigned short* Ch = (unsigned short*)Cv + (size_t)z * sC;
    const float* rp = resid ? resid + (size_t)z * sR : nullptr;

    #pragma unroll
    for (int fm = 0; fm < 4; ++fm) {
        #pragma unroll
        for (int fn = 0; fn < 4; ++fn) {
            int col = n0 + wc * 64 + fn * 16 + lr;          // D col = lane&15
            int rowb = m0 + wr * 64 + fm * 16 + lk * 4;     // D row = 4*(lane>>4)+j
            #pragma unroll
            for (int j = 0; j < 4; ++j) {
                int row = rowb + j;
                float v = acc[fm][fn][j];
                if (BIAS_MODE == 1) v += bias[col];
                if (BIAS_MODE == 2) v += bias[row];
                v *= alpha;
                if (RESID) v += rp[(size_t)row * ldc + col];
                if (OUT_F32) Cf[(size_t)row * ldc + col] = v;
                else         Ch[(size_t)row * ldc + col] = f2bf(v);
            }
        }
    }
}

// Fused attention: per block = 1 batch x 128 q-rows (8 waves x 16 rows).
// Q[B][N][C] (pre-scaled), K[B][N][C], V[B][C][N] -> H[B][N][C], all bf16.
__global__ __launch_bounds__(512, 2)
void flash_attn(const unsigned short* __restrict__ Q,
                const unsigned short* __restrict__ Kg,
                const unsigned short* __restrict__ Vg,
                unsigned short* __restrict__ H)
{
    __shared__ __align__(16) unsigned short Ks[64 * 512];   // 64 KB
    __shared__ __align__(16) unsigned short Vs[512 * 64];   // 64 KB
    __shared__ __align__(16) unsigned short Ps[8][16 * 72]; // 18 KB (144B row pitch)

    // XCD-affinity decode: physical p%8 selects XCD; keep batch b on one XCD
    const int p = blockIdx.x;
    const int b  = ((p >> 6) << 3) + (p & 7);
    const int qt = (p >> 3) & 7;

    const int tid = threadIdx.x;
    const int w = tid >> 6, lane = tid & 63;
    const int lr = lane & 15, lk = lane >> 4;
    const int q0 = qt * 128 + w * 16;

    // Q A-fragments in registers: lane holds Q[q0+lr][ck*32 + lk*8 + e]
    bf16x8 qf[16];
    const unsigned short* qp = Q + ((size_t)b * NSP + q0 + lr) * CD + lk * 8;
    #pragma unroll
    for (int ck = 0; ck < 16; ++ck) qf[ck] = *(const bf16x8*)(qp + ck * 32);

    f32x4 o[32] = {};
    float mr[4], ls[4];
    #pragma unroll
    for (int j = 0; j < 4; ++j) { mr[j] = -3.0e38f; ls[j] = 0.f; }

    const unsigned short* Kb = Kg + (size_t)b * NSP * CD;
    const unsigned short* Vb = Vg + (size_t)b * CD * NSP;

    for (int t = 0; t < 16; ++t) {
        const int kv0 = t * 64;
        __syncthreads();
        // stage K tile [64][512]: one wave-call = 1 row (64 chunks of 16B)
        #pragma unroll
        for (int i = 0; i < 8; ++i) {
            int row = i * 8 + w;
            int ch = lane ^ (row & 7);
            gl_lds16(Kb + (size_t)(kv0 + row) * CD + ch * 8, &Ks[row * 512]);
        }
        // stage V tile [512][64]: one wave-call = 8 rows (8 chunks each)
        #pragma unroll
        for (int i = 0; i < 8; ++i) {
            int rb = i * 64 + w * 8;
            int row = rb + (lane >> 3);
            int ch = (lane & 7) ^ (row & 7);
            gl_lds16(Vb + (size_t)row * NSP + kv0 + ch * 8, &Vs[rb * 64]);
        }
        __syncthreads();

        // S = Q K^T  (16q x 64m per wave)
        f32x4 s[4] = {};
        #pragma unroll
        for (int st = 0; st < 16; ++st) {
            #pragma unroll
            for (int fm = 0; fm < 4; ++fm) {
                int r = fm * 16 + lr;
                int cs = (st * 4 + lk) ^ (r & 7);
                bf16x8 kf = *(const bf16x8*)&Ks[r * 512 + cs * 8];
                s[fm] = __builtin_amdgcn_mfma_f32_16x16x32_bf16(qf[st], kf, s[fm], 0, 0, 0);
            }
        }

        // online softmax; lane owns rows lk*4+j, cols fm*16+lr
        float pm[4];
        #pragma unroll
        for (int j = 0; j < 4; ++j)
            pm[j] = fmaxf(fmaxf(s[0][j], s[1][j]), fmaxf(s[2][j], s[3][j]));
        #pragma unroll
        for (int off = 1; off < 16; off <<= 1) {
            #pragma unroll
            for (int j = 0; j < 4; ++j) pm[j] = fmaxf(pm[j], __shfl_xor(pm[j], off));
        }
        float need = fmaxf(fmaxf(pm[0] - mr[0], pm[1] - mr[1]),
                           fmaxf(pm[2] - mr[2], pm[3] - mr[3]));
        if (!__all(need <= 8.0f)) {   // T13 defer-max: rescale only on real growth
            #pragma unroll
            for (int j = 0; j < 4; ++j) {
                float mn = fmaxf(mr[j], pm[j]);
                float sc = __expf(mr[j] - mn);
                mr[j] = mn; ls[j] *= sc;
                #pragma unroll
                for (int ns = 0; ns < 32; ++ns) o[ns][j] *= sc;
            }
        }
        float rs[4] = {0.f, 0.f, 0.f, 0.f};
        #pragma unroll
        for (int fm = 0; fm < 4; ++fm) {
            #pragma unroll
            for (int j = 0; j < 4; ++j) {
                float pv = __expf(s[fm][j] - mr[j]);
                rs[j] += pv;
                Ps[w][(lk * 4 + j) * 72 + fm * 16 + lr] = f2bf(pv);
            }
        }
        #pragma unroll
        for (int off = 1; off < 16; off <<= 1) {
            #pragma unroll
            for (int j = 0; j < 4; ++j) rs[j] += __shfl_xor(rs[j], off);
        }
        #pragma unroll
        for (int j = 0; j < 4; ++j) ls[j] += rs[j];

        // P -> A-frags (same-wave LDS round trip; compiler inserts lgkmcnt)
        bf16x8 pa0 = *(const bf16x8*)&Ps[w][lr * 72 + lk * 8];
        bf16x8 pa1 = *(const bf16x8*)&Ps[w][lr * 72 + 32 + lk * 8];

        // O += P * V^T : B operand rows = channels (Vs rows), k = m
        #pragma unroll
        for (int ns = 0; ns < 32; ++ns) {
            int rc = ns * 16 + lr;
            int c0 = lk ^ (rc & 7);
            int c1 = (4 + lk) ^ (rc & 7);
            bf16x8 v0 = *(const bf16x8*)&Vs[rc * 64 + c0 * 8];
            bf16x8 v1 = *(const bf16x8*)&Vs[rc * 64 + c1 * 8];
            o[ns] = __builtin_amdgcn_mfma_f32_16x16x32_bf16(pa0, v0, o[ns], 0, 0, 0);
            o[ns] = __builtin_amdgcn_mfma_f32_16x16x32_bf16(pa1, v1, o[ns], 0, 0, 0);
        }
    }

    float inv[4];
    #pragma unroll
    for (int j = 0; j < 4; ++j) inv[j] = 1.f / ls[j];
    unsigned short* Hp = H + ((size_t)b * NSP + q0) * CD;
    #pragma unroll
    for (int ns = 0; ns < 32; ++ns) {
        #pragma unroll
        for (int j = 0; j < 4; ++j)
            Hp[(size_t)(lk * 4 + j) * CD + ns * 16 + lr] = f2bf(o[ns][j] * inv[j]);
    }
}

extern "C" void kernel_launch(void* const* d_in, const int* in_sizes, int n_in,
                              void* d_out, int out_size, void* d_ws, size_t ws_size,
                              hipStream_t stream)
{
    const float* x  = (const float*)d_in[0];
    const float* Wq = (const float*)d_in[1];
    const float* bq = (const float*)d_in[2];
    const float* Wk = (const float*)d_in[3];
    const float* bk = (const float*)d_in[4];
    const float* Wv = (const float*)d_in[5];
    const float* bv = (const float*)d_in[6];
    const float* Wo = (const float*)d_in[7];
    const float* bo = (const float*)d_in[8];
    float* out = (float*)d_out;

    unsigned short* w   = (unsigned short*)d_ws;
    unsigned short* Wqb = w;
    unsigned short* Wkb = Wqb + 262144;
    unsigned short* Wvb = Wkb + 262144;
    unsigned short* Wob = Wvb + 262144;
    unsigned short* Xt  = Wob + 262144;      // [B][N][C]
    unsigned short* Qb  = Xt + 16777216;     // [B][N][C]
    unsigned short* Kb  = Qb + 16777216;     // [B][N][C]
    unsigned short* Vc  = Kb + 16777216;     // [B][C][N]
    unsigned short* Hb  = Xt;                // reuse Xt (dead after V gemm)

    cvt_w<<<1024, 256, 0, stream>>>(Wq, Wqb, 262144);
    cvt_w<<<1024, 256, 0, stream>>>(Wk, Wkb, 262144);
    cvt_w<<<1024, 256, 0, stream>>>(Wv, Wvb, 262144);
    cvt_w<<<1024, 256, 0, stream>>>(Wo, Wob, 262144);
    transpose_x<<<dim3(32, 16, 32), dim3(32, 8), 0, stream>>>(x, Xt);

    // Q = (Xt*Wq^T + bq) * C^-0.5  (scale folded); K = Xt*Wk^T + bk
    gemm_bt<1, false, false><<<dim3(4, 256, 1), 256, 0, stream>>>(
        Xt, Wqb, Qb, bq, nullptr, 512, 512, 512, 512, 0, 0, 0, 0, 0.04419417382f);
    gemm_bt<1, false, false><<<dim3(4, 256, 1), 256, 0, stream>>>(
        Xt, Wkb, Kb, bk, nullptr, 512, 512, 512, 512, 0, 0, 0, 0, 1.0f);

    // V in [C][N]: A=Wv [C,C], B=Xt_b [N,C], bias per-row(c)
    gemm_bt<2, false, false><<<dim3(8, 4, 32), 256, 0, stream>>>(
        Wvb, Xt, Vc, bv, nullptr, 512, 512, 512, 1024, 0, 524288, 524288, 0, 1.0f);

    // fused attention -> Hb [B][N][C]
    flash_attn<<<256, 512, 0, stream>>>(Qb, Kb, Vc, Hb);

    // out = Wo * H_b^T + bo(row) + x   [C][N] fp32
    gemm_bt<2, true, true><<<dim3(8, 4, 32), 256, 0, stream>>>(
        Wob, Hb, out, bo, x, 512, 512, 512, 1024,
        0, 524288, 524288, 524288, 1.0f);
}